// Round 2
// baseline (417.850 us; speedup 1.0000x reference)
//
#include <hip/hip_runtime.h>
#include <hip/hip_fp16.h>

#define F_IN 61
#define H 32
#define BUCK_BITS 8                  // 256 nodes per bucket
#define BUCK_SZ   256
#define CHUNK     8192               // edges per block in hist/bin passes

static __device__ __forceinline__ __half2 h2_shfl_xor(__half2 v, int m) {
    int iv; __builtin_memcpy(&iv, &v, sizeof(iv));
    iv = __shfl_xor(iv, m, 32);
    __half2 o; __builtin_memcpy(&o, &iv, sizeof(o));
    return o;
}

// ---------- scan level 1: per-256-block exclusive scan + block totals ----------
__global__ __launch_bounds__(256) void scan1_kernel(const int* __restrict__ in,
                                                    int* __restrict__ scanned,
                                                    int* __restrict__ btot, int n) {
    __shared__ int s[256];
    int tid = threadIdx.x;
    int i = blockIdx.x * 256 + tid;
    int v = (i < n) ? in[i] : 0;
    s[tid] = v;
    __syncthreads();
    for (int off = 1; off < 256; off <<= 1) {
        int t = (tid >= off) ? s[tid - off] : 0;
        __syncthreads();
        s[tid] += t;
        __syncthreads();
    }
    if (i < n) scanned[i] = s[tid] - v;
    if (tid == 255) btot[blockIdx.x] = s[255];
}

// ---------- scan level 2: exclusive scan of block totals (single block) ----------
__global__ __launch_bounds__(1024) void scan2_kernel(int* __restrict__ btot, int nB) {
    __shared__ int s[1024];
    int tid = threadIdx.x;
    int v = (tid < nB) ? btot[tid] : 0;
    s[tid] = v;
    __syncthreads();
    for (int off = 1; off < 1024; off <<= 1) {
        int t = (tid >= off) ? s[tid - off] : 0;
        __syncthreads();
        s[tid] += t;
        __syncthreads();
    }
    if (tid < nB) btot[tid] = s[tid] - v;
}

// ---------- pass A: per-(block,bucket) histogram; block 0 also zeroes gs ----------
__global__ __launch_bounds__(256) void histA_kernel(const int* __restrict__ ei,
                                                    int* __restrict__ counts,
                                                    float* __restrict__ gs,
                                                    int E, int B, int nbuck) {
    __shared__ int h[640];
    int tid = threadIdx.x;
    if (blockIdx.x == 0) {
        #pragma unroll
        for (int r = 0; r < 8; r++) gs[r * 256 + tid] = 0.f;   // 64*H floats
    }
    for (int i = tid; i < nbuck; i += 256) h[i] = 0;
    __syncthreads();
    int e0 = blockIdx.x * CHUNK;
    int e1 = e0 + CHUNK; if (e1 > E) e1 = E;
    for (int e = e0 + tid; e < e1; e += 256)
        atomicAdd(&h[ei[E + e] >> BUCK_BITS], 1);
    __syncthreads();
    for (int i = tid; i < nbuck; i += 256) counts[i * B + blockIdx.x] = h[i];
}

// ---------- pass B: bin edges into per-(block,bucket) EXCLUSIVE ranges ----------
// Reads scan results directly (scan3 folded): excl[i] = countsS[i] + btot[i>>8].
// pack = (src<<8)|(dst&255); src < 2^18 fits.
__global__ __launch_bounds__(256) void binB_kernel(const int* __restrict__ ei,
                                                   const int* __restrict__ countsS,
                                                   const int* __restrict__ btot,
                                                   int* __restrict__ tmp,
                                                   int E, int B, int nbuck) {
    __shared__ int lcur[640];
    int tid = threadIdx.x;
    for (int i = tid; i < nbuck; i += 256) {
        int ci = i * B + blockIdx.x;
        lcur[i] = countsS[ci] + btot[ci >> 8];
    }
    __syncthreads();
    int e0 = blockIdx.x * CHUNK;
    int e1 = e0 + CHUNK; if (e1 > E) e1 = E;
    for (int e = e0 + tid; e < e1; e += 256) {
        int s = ei[e];
        int d = ei[E + e];
        int pos = atomicAdd(&lcur[d >> BUCK_BITS], 1);
        tmp[pos] = (s << BUCK_BITS) | (d & (BUCK_SZ - 1));
    }
}

// ---------- pass C: per-bucket degree + row_start + dinv + final CSR scatter ----------
// src_sorted stores BYTE offsets (src*64) for the fp16 row table.
// Block 0 also writes the zero rows (index N) of both fp16 buffers.
__global__ __launch_bounds__(256) void binC_kernel(const int* __restrict__ countsS,
                                                   const int* __restrict__ btot,
                                                   const int* __restrict__ tmp,
                                                   int* __restrict__ src_sorted,
                                                   int* __restrict__ row_start,
                                                   float* __restrict__ dinv,
                                                   __half* __restrict__ bufA,
                                                   __half* __restrict__ bufB,
                                                   int N, int E, int B, int nbuck) {
    __shared__ int hist[BUCK_SZ];
    __shared__ int pre[BUCK_SZ];
    __shared__ int lcur[BUCK_SZ];
    int tid = threadIdx.x;
    int b = blockIdx.x;
    int base = b << BUCK_BITS;
    if (b == 0 && tid < H) {                 // zero rows for padded gathers
        bufA[(size_t)N * H + tid] = __float2half(0.f);
        bufB[(size_t)N * H + tid] = __float2half(0.f);
    }
    int c0 = b * B;
    int e0 = countsS[c0] + btot[c0 >> 8];
    int e1 = E;
    if (b + 1 < nbuck) {
        int c1 = (b + 1) * B;
        e1 = countsS[c1] + btot[c1 >> 8];
    }
    hist[tid] = 0;
    __syncthreads();
    for (int e = e0 + tid; e < e1; e += 256)
        atomicAdd(&hist[tmp[e] & (BUCK_SZ - 1)], 1);
    __syncthreads();
    int v = hist[tid];
    pre[tid] = v;
    __syncthreads();
    for (int off = 1; off < 256; off <<= 1) {
        int t = (tid >= off) ? pre[tid - off] : 0;
        __syncthreads();
        pre[tid] += t;
        __syncthreads();
    }
    int excl = pre[tid] - v;
    int node = base + tid;
    if (node < N) {
        row_start[node] = e0 + excl;
        dinv[node] = rsqrtf((float)v + 1.0f);     // +1 self-loop
        if (node == N - 1) row_start[N] = E;
    }
    lcur[tid] = e0 + excl;
    __syncthreads();
    for (int e = e0 + tid; e < e1; e += 256) {
        int p = tmp[e];
        int pos = atomicAdd(&lcur[p & (BUCK_SZ - 1)], 1);
        src_sorted[pos] = (p >> BUCK_BITS) << 6;   // byte offset of fp16 row
    }
}

// ---------- layer 1 dense: hs1 = fp16( dinv * (x @ W1) ) ----------
// 32 nodes/block (4x amortized W staging vs 8/block). W staged via 2 float4
// global loads/thread into pair-interleaved Wp[k2*64 + 2f + (kk&1)] (odd slots
// of k2=30 unused; kk=60 handled as a scalar tail). x staged via 2 float4
// loads/thread into unpadded xs[32*61]. Compute shares the ds_read_b64 W
// fragment across 4 nodes; x pair reads are LDS broadcasts (ds_read2_b32).
__global__ __launch_bounds__(256) void gemm1_kernel(const float* __restrict__ x,
                                                    const float* __restrict__ W,
                                                    const float* __restrict__ dinv,
                                                    __half* __restrict__ h, int N) {
    __shared__ float Wp[31 * 64];
    __shared__ float xs[32 * F_IN];
    int tid = threadIdx.x;
    // stage W: 61*32 = 1952 floats = 488 float4; rows are 32 floats -> no row straddle
    #pragma unroll
    for (int c = tid; c < 488; c += 256) {
        float4 v = ((const float4*)W)[c];
        int g = c << 2;
        int kk = g >> 5, f0 = g & 31;
        int dstb = ((kk >> 1) << 6) + (kk & 1);
        Wp[dstb + (f0 << 1) + 0] = v.x;
        Wp[dstb + (f0 << 1) + 2] = v.y;
        Wp[dstb + (f0 << 1) + 4] = v.z;
        Wp[dstb + (f0 << 1) + 6] = v.w;
    }
    int nb = blockIdx.x * 32;
    int navail = N - nb; if (navail > 32) navail = 32;
    const float* xb = x + (long long)nb * F_IN;
    int lim = navail * F_IN;                 // 1952 for full blocks
    #pragma unroll
    for (int c = tid; c < 488; c += 256) {
        int g = c << 2;
        float4 v;
        if (g + 4 <= lim) {
            v = *(const float4*)(xb + g);
        } else {
            v = make_float4(0.f, 0.f, 0.f, 0.f);
            if (g + 0 < lim) v.x = xb[g + 0];
            if (g + 1 < lim) v.y = xb[g + 1];
            if (g + 2 < lim) v.z = xb[g + 2];
        }
        *(float4*)&xs[g] = v;
    }
    __syncthreads();
    int nl = tid >> 5, f = tid & 31;
    const int b0 = (nl + 0)  * F_IN;
    const int b1 = (nl + 8)  * F_IN;
    const int b2 = (nl + 16) * F_IN;
    const int b3 = (nl + 24) * F_IN;
    float s0 = 0.f, s1 = 0.f, s2 = 0.f, s3 = 0.f;
    #pragma unroll
    for (int k2 = 0; k2 < 30; k2++) {
        float2 wv = *(const float2*)&Wp[(k2 << 6) + (f << 1)];
        int ko = k2 << 1;
        s0 += xs[b0 + ko] * wv.x + xs[b0 + ko + 1] * wv.y;
        s1 += xs[b1 + ko] * wv.x + xs[b1 + ko + 1] * wv.y;
        s2 += xs[b2 + ko] * wv.x + xs[b2 + ko + 1] * wv.y;
        s3 += xs[b3 + ko] * wv.x + xs[b3 + ko + 1] * wv.y;
    }
    {   // tail kk = 60 (even slot of k2 = 30; odd slots never read)
        float wl = Wp[(30 << 6) + (f << 1)];
        s0 += xs[b0 + 60] * wl;
        s1 += xs[b1 + 60] * wl;
        s2 += xs[b2 + 60] * wl;
        s3 += xs[b3 + 60] * wl;
    }
    int n0 = nb + nl;
    if (n0 < N)      h[(long long)(n0)      * H + f] = __float2half(s0 * dinv[n0]);
    if (n0 + 8 < N)  h[(long long)(n0 + 8)  * H + f] = __float2half(s1 * dinv[n0 + 8]);
    if (n0 + 16 < N) h[(long long)(n0 + 16) * H + f] = __float2half(s2 * dinv[n0 + 16]);
    if (n0 + 24 < N) h[(long long)(n0 + 24) * H + f] = __float2half(s3 * dinv[n0 + 24]);
}

// ---------- fused agg + GEMM (dwordx2 gathers, 4 edge slots per 32-lane group) ----
// Lane map per node (32 lanes): slot = lane>>3 (edge slot 0..3), fq = lane&7
// (feature quad: bytes 8*fq of the 64B row). One dwordx2 load instr covers 4
// rows per group (8 per wave) — half the load/shfl instruction count of the
// dword version at identical gathered bytes. Slot reduction = 2 shfl_xor levels.
// Invalid slots gather the ZERO ROW at byte offset N*64.
// Dense 32x32 epilogue reads pair-interleaved W^T (2-way bank alias = free).
__global__ __launch_bounds__(256) void agg_gemm_kernel(const int* __restrict__ row_start,
                                                       const int* __restrict__ src_sorted,
                                                       const float* __restrict__ dinv,
                                                       const __half* __restrict__ hs,
                                                       const float* __restrict__ b,
                                                       const float* __restrict__ Wn,
                                                       __half* __restrict__ hout, int N) {
    __shared__ float Wp[16 * 64];          // Wp[k2*64 + 2f + (k&1)] = Wn[k*32+f]
    __shared__ float t[8 * H];
    int tid = threadIdx.x;
    for (int i = tid; i < 1024; i += 256) {
        int k2 = i >> 6, rem = i & 63;
        int f = rem >> 1, kk = (k2 << 1) | (rem & 1);
        Wp[i] = Wn[kk * H + f];
    }
    int nl = tid >> 5;
    int lane32 = tid & 31;
    int slot = lane32 >> 3;
    int fq = lane32 & 7;
    int node = blockIdx.x * 8 + nl;
    int zoff = N << 6;
    __half2 z = __floats2half2_rn(0.f, 0.f);
    __half2 a0 = z, a1 = z, a2 = z, a3 = z;
    if (node < N) {
        const char* hbase = (const char*)hs + (fq << 3);
        int e0 = row_start[node], e1 = row_start[node + 1];
        int idxv = (e0 + lane32 < e1) ? src_sorted[e0 + lane32] : zoff;
        for (int base = e0; base < e1; base += 32) {
            int w = e1 - base; if (w > 32) w = 32;
            int idxN = (base + 32 + lane32 < e1) ? src_sorted[base + 32 + lane32] : zoff;
            for (int j = 0; j < w; j += 16) {
                int offs[4];
                #pragma unroll
                for (int k = 0; k < 4; k++) offs[k] = __shfl(idxv, j + (k << 2) + slot, 32);
                uint2 g[4];
                #pragma unroll
                for (int k = 0; k < 4; k++) g[k] = *(const uint2*)(hbase + offs[k]);
                a0 = __hadd2(a0, *(__half2*)&g[0].x);
                a1 = __hadd2(a1, *(__half2*)&g[0].y);
                a2 = __hadd2(a2, *(__half2*)&g[1].x);
                a3 = __hadd2(a3, *(__half2*)&g[1].y);
                a0 = __hadd2(a0, *(__half2*)&g[2].x);
                a1 = __hadd2(a1, *(__half2*)&g[2].y);
                a2 = __hadd2(a2, *(__half2*)&g[3].x);
                a3 = __hadd2(a3, *(__half2*)&g[3].y);
            }
            idxv = idxN;
        }
    }
    a0 = __hadd2(a0, a2);
    a1 = __hadd2(a1, a3);
    a0 = __hadd2(a0, h2_shfl_xor(a0, 8));
    a1 = __hadd2(a1, h2_shfl_xor(a1, 8));
    a0 = __hadd2(a0, h2_shfl_xor(a0, 16));
    a1 = __hadd2(a1, h2_shfl_xor(a1, 16));
    if (node < N && lane32 < 8) {
        float di = dinv[node];
        uint2 sv = *(const uint2*)((const char*)hs + ((long long)node << 6) + (fq << 3));
        float2 f0 = __half22float2(a0), f1 = __half22float2(a1);
        float2 s0 = __half22float2(*(__half2*)&sv.x);
        float2 s1 = __half22float2(*(__half2*)&sv.y);
        float4 bv = ((const float4*)b)[fq];
        float4 r;
        r.x = fmaxf(di * (f0.x + s0.x) + bv.x, 0.f);
        r.y = fmaxf(di * (f0.y + s0.y) + bv.y, 0.f);
        r.z = fmaxf(di * (f1.x + s1.x) + bv.z, 0.f);
        r.w = fmaxf(di * (f1.y + s1.y) + bv.w, 0.f);
        ((float4*)&t[nl * H])[fq] = r;
    }
    __syncthreads();
    if (node < N) {
        int f = lane32;
        float s = 0.f;
        #pragma unroll
        for (int k2 = 0; k2 < 16; k2++) {
            float2 xv = *(const float2*)&t[nl * H + (k2 << 1)];
            float2 wv = *(const float2*)&Wp[(k2 << 6) + (f << 1)];
            s += xv.x * wv.x + xv.y * wv.y;
        }
        hout[(long long)node * H + f] = __float2half(s * dinv[node]);
    }
}

// ---------- final layer: X5 = relu(...), pool into 64 spread copies ----------
__global__ __launch_bounds__(256) void agg_pool_kernel(const int* __restrict__ row_start,
                                                       const int* __restrict__ src_sorted,
                                                       const float* __restrict__ dinv,
                                                       const __half* __restrict__ hs,
                                                       const float* __restrict__ b,
                                                       float* __restrict__ gs, int N) {
    __shared__ float t[8 * H];
    int tid = threadIdx.x;
    int nl = tid >> 5;
    int lane32 = tid & 31;
    int slot = lane32 >> 3;
    int fq = lane32 & 7;
    int node = blockIdx.x * 8 + nl;
    int zoff = N << 6;
    __half2 z = __floats2half2_rn(0.f, 0.f);
    __half2 a0 = z, a1 = z, a2 = z, a3 = z;
    if (node < N) {
        const char* hbase = (const char*)hs + (fq << 3);
        int e0 = row_start[node], e1 = row_start[node + 1];
        int idxv = (e0 + lane32 < e1) ? src_sorted[e0 + lane32] : zoff;
        for (int base = e0; base < e1; base += 32) {
            int w = e1 - base; if (w > 32) w = 32;
            int idxN = (base + 32 + lane32 < e1) ? src_sorted[base + 32 + lane32] : zoff;
            for (int j = 0; j < w; j += 16) {
                int offs[4];
                #pragma unroll
                for (int k = 0; k < 4; k++) offs[k] = __shfl(idxv, j + (k << 2) + slot, 32);
                uint2 g[4];
                #pragma unroll
                for (int k = 0; k < 4; k++) g[k] = *(const uint2*)(hbase + offs[k]);
                a0 = __hadd2(a0, *(__half2*)&g[0].x);
                a1 = __hadd2(a1, *(__half2*)&g[0].y);
                a2 = __hadd2(a2, *(__half2*)&g[1].x);
                a3 = __hadd2(a3, *(__half2*)&g[1].y);
                a0 = __hadd2(a0, *(__half2*)&g[2].x);
                a1 = __hadd2(a1, *(__half2*)&g[2].y);
                a2 = __hadd2(a2, *(__half2*)&g[3].x);
                a3 = __hadd2(a3, *(__half2*)&g[3].y);
            }
            idxv = idxN;
        }
    }
    a0 = __hadd2(a0, a2);
    a1 = __hadd2(a1, a3);
    a0 = __hadd2(a0, h2_shfl_xor(a0, 8));
    a1 = __hadd2(a1, h2_shfl_xor(a1, 8));
    a0 = __hadd2(a0, h2_shfl_xor(a0, 16));
    a1 = __hadd2(a1, h2_shfl_xor(a1, 16));
    if (lane32 < 8) {
        float4 r = make_float4(0.f, 0.f, 0.f, 0.f);
        if (node < N) {
            float di = dinv[node];
            uint2 sv = *(const uint2*)((const char*)hs + ((long long)node << 6) + (fq << 3));
            float2 f0 = __half22float2(a0), f1 = __half22float2(a1);
            float2 s0 = __half22float2(*(__half2*)&sv.x);
            float2 s1 = __half22float2(*(__half2*)&sv.y);
            float4 bv = ((const float4*)b)[fq];
            r.x = fmaxf(di * (f0.x + s0.x) + bv.x, 0.f);
            r.y = fmaxf(di * (f0.y + s0.y) + bv.y, 0.f);
            r.z = fmaxf(di * (f1.x + s1.x) + bv.z, 0.f);
            r.w = fmaxf(di * (f1.y + s1.y) + bv.w, 0.f);
        }
        ((float4*)&t[nl * H])[fq] = r;
    }
    __syncthreads();
    if (tid < H) {
        float s = 0.f;
        #pragma unroll
        for (int rI = 0; rI < 8; rI++) s += t[rI * H + tid];
        atomicAdd(&gs[(blockIdx.x & 63) * H + tid], s);
    }
}

// ---------- head ----------
__global__ __launch_bounds__(64) void head_kernel(const float* __restrict__ gs,
                                                  const float* __restrict__ Wl1,
                                                  const float* __restrict__ bl1,
                                                  const float* __restrict__ Wl2,
                                                  const float* __restrict__ bl2,
                                                  float* __restrict__ out) {
    __shared__ float gg[H];
    __shared__ float t[16];
    int tid = threadIdx.x;
    if (tid < H) {
        float s = 0.f;
        for (int c = 0; c < 64; c++) s += gs[c * H + tid];
        gg[tid] = s;
    }
    __syncthreads();
    if (tid < 16) {
        float s = bl1[tid];
        #pragma unroll
        for (int k = 0; k < 32; k++) s += gg[k] * Wl1[k * 16 + tid];
        t[tid] = fmaxf(s, 0.f);
    }
    __syncthreads();
    if (tid < 3) {
        float s = bl2[tid];
        #pragma unroll
        for (int k = 0; k < 16; k++) s += t[k] * Wl2[k * 3 + tid];
        out[tid] = s;
    }
}

extern "C" void kernel_launch(void* const* d_in, const int* in_sizes, int n_in,
                              void* d_out, int out_size, void* d_ws, size_t ws_size,
                              hipStream_t stream) {
    const float* x   = (const float*)d_in[0];
    const int*   ei  = (const int*)d_in[1];
    const float* W1  = (const float*)d_in[2];
    const float* b1  = (const float*)d_in[3];
    const float* W2  = (const float*)d_in[4];
    const float* b2  = (const float*)d_in[5];
    const float* W3  = (const float*)d_in[6];
    const float* b3  = (const float*)d_in[7];
    const float* W4  = (const float*)d_in[8];
    const float* b4  = (const float*)d_in[9];
    const float* Wl1 = (const float*)d_in[10];
    const float* bl1 = (const float*)d_in[11];
    const float* Wl2 = (const float*)d_in[12];
    const float* bl2 = (const float*)d_in[13];
    float* out = (float*)d_out;

    const int N = in_sizes[0] / F_IN;
    const int E = in_sizes[1] / 2;
    const int nbuck = (N + BUCK_SZ - 1) >> BUCK_BITS;      // 586 for N=150000
    const int B = (E + CHUNK - 1) / CHUNK;                 // 293 for E=2.4M
    const int nC = nbuck * B;

    char* ws = (char*)d_ws;
    size_t off = 0;
    auto alloc = [&](size_t bytes) {
        char* p = ws + off;
        off += (bytes + 255) & ~(size_t)255;
        return p;
    };
    float* dinv       = (float*)alloc((size_t)N * 4);
    int*   row_start  = (int*)alloc((size_t)(N + 1) * 4);
    int*   counts     = (int*)alloc((size_t)nC * 4);
    int*   countsS    = (int*)alloc((size_t)nC * 4);
    int*   btot2      = (int*)alloc(((size_t)nC / 256 + 2) * 4);
    int*   src_sorted = (int*)alloc((size_t)E * 4);
    int*   tmp        = (int*)alloc((size_t)E * 4);
    __half* bufA      = (__half*)alloc((size_t)(N + 1) * H * 2);   // fp16 rows + zero row
    __half* bufB      = (__half*)alloc((size_t)(N + 1) * H * 2);
    float* gs         = (float*)alloc(64 * H * 4);

    const int TB = 256;
    const int gC  = (nC + TB - 1) / TB;   // 675 blocks <= 1024 for scan2
    const int gN8 = (N + 7) / 8;
    const int gN32 = (N + 31) / 32;

    // ---- CSR build (no global atomics, no memsets — all folded) ----
    histA_kernel<<<B, TB, 0, stream>>>(ei, counts, gs, E, B, nbuck);
    scan1_kernel<<<gC, TB, 0, stream>>>(counts, countsS, btot2, nC);
    scan2_kernel<<<1, 1024, 0, stream>>>(btot2, gC);
    binB_kernel<<<B, TB, 0, stream>>>(ei, countsS, btot2, tmp, E, B, nbuck);
    binC_kernel<<<nbuck, TB, 0, stream>>>(countsS, btot2, tmp, src_sorted, row_start,
                                          dinv, bufA, bufB, N, E, B, nbuck);

    // ---- layers ----
    gemm1_kernel<<<gN32, TB, 0, stream>>>(x, W1, dinv, bufA, N);                                 // hs1
    agg_gemm_kernel<<<gN8, TB, 0, stream>>>(row_start, src_sorted, dinv, bufA, b1, W2, bufB, N); // hs2
    agg_gemm_kernel<<<gN8, TB, 0, stream>>>(row_start, src_sorted, dinv, bufB, b2, W3, bufA, N); // hs3
    agg_gemm_kernel<<<gN8, TB, 0, stream>>>(row_start, src_sorted, dinv, bufA, b3, W4, bufB, N); // hs4
    agg_pool_kernel<<<gN8, TB, 0, stream>>>(row_start, src_sorted, dinv, bufB, b4, gs, N);       // pool(X5)

    head_kernel<<<1, 64, 0, stream>>>(gs, Wl1, bl1, Wl2, bl2, out);
}

// Round 3
// 378.045 us; speedup vs baseline: 1.1053x; 1.1053x over previous
//
#include <hip/hip_runtime.h>
#include <hip/hip_fp16.h>

#define F_IN 61
#define H 32
#define BUCK_BITS 8                  // 256 nodes per bucket
#define BUCK_SZ   256
#define CHUNK     8192               // edges per block in hist/bin passes

static __device__ __forceinline__ __half2 h2_shfl_xor(__half2 v, int m) {
    int iv; __builtin_memcpy(&iv, &v, sizeof(iv));
    iv = __shfl_xor(iv, m, 32);
    __half2 o; __builtin_memcpy(&o, &iv, sizeof(o));
    return o;
}

// ---------- scan level 1: per-256-block exclusive scan + block totals ----------
__global__ __launch_bounds__(256) void scan1_kernel(const int* __restrict__ in,
                                                    int* __restrict__ scanned,
                                                    int* __restrict__ btot, int n) {
    __shared__ int s[256];
    int tid = threadIdx.x;
    int i = blockIdx.x * 256 + tid;
    int v = (i < n) ? in[i] : 0;
    s[tid] = v;
    __syncthreads();
    for (int off = 1; off < 256; off <<= 1) {
        int t = (tid >= off) ? s[tid - off] : 0;
        __syncthreads();
        s[tid] += t;
        __syncthreads();
    }
    if (i < n) scanned[i] = s[tid] - v;
    if (tid == 255) btot[blockIdx.x] = s[255];
}

// ---------- scan level 2: exclusive scan of block totals (single block) ----------
__global__ __launch_bounds__(1024) void scan2_kernel(int* __restrict__ btot, int nB) {
    __shared__ int s[1024];
    int tid = threadIdx.x;
    int v = (tid < nB) ? btot[tid] : 0;
    s[tid] = v;
    __syncthreads();
    for (int off = 1; off < 1024; off <<= 1) {
        int t = (tid >= off) ? s[tid - off] : 0;
        __syncthreads();
        s[tid] += t;
        __syncthreads();
    }
    if (tid < nB) btot[tid] = s[tid] - v;
}

// ---------- pass A: per-(block,bucket) histogram; block 0 also zeroes gs ----------
__global__ __launch_bounds__(256) void histA_kernel(const int* __restrict__ ei,
                                                    int* __restrict__ counts,
                                                    float* __restrict__ gs,
                                                    int E, int B, int nbuck) {
    __shared__ int h[640];
    int tid = threadIdx.x;
    if (blockIdx.x == 0) {
        #pragma unroll
        for (int r = 0; r < 8; r++) gs[r * 256 + tid] = 0.f;   // 64*H floats
    }
    for (int i = tid; i < nbuck; i += 256) h[i] = 0;
    __syncthreads();
    int e0 = blockIdx.x * CHUNK;
    int e1 = e0 + CHUNK; if (e1 > E) e1 = E;
    for (int e = e0 + tid; e < e1; e += 256)
        atomicAdd(&h[ei[E + e] >> BUCK_BITS], 1);
    __syncthreads();
    for (int i = tid; i < nbuck; i += 256) counts[i * B + blockIdx.x] = h[i];
}

// ---------- pass B: bin edges into per-(block,bucket) EXCLUSIVE ranges ----------
// Reads scan results directly (scan3 folded): excl[i] = countsS[i] + btot[i>>8].
// pack = (src<<8)|(dst&255); src < 2^18 fits.
__global__ __launch_bounds__(256) void binB_kernel(const int* __restrict__ ei,
                                                   const int* __restrict__ countsS,
                                                   const int* __restrict__ btot,
                                                   int* __restrict__ tmp,
                                                   int E, int B, int nbuck) {
    __shared__ int lcur[640];
    int tid = threadIdx.x;
    for (int i = tid; i < nbuck; i += 256) {
        int ci = i * B + blockIdx.x;
        lcur[i] = countsS[ci] + btot[ci >> 8];
    }
    __syncthreads();
    int e0 = blockIdx.x * CHUNK;
    int e1 = e0 + CHUNK; if (e1 > E) e1 = E;
    for (int e = e0 + tid; e < e1; e += 256) {
        int s = ei[e];
        int d = ei[E + e];
        int pos = atomicAdd(&lcur[d >> BUCK_BITS], 1);
        tmp[pos] = (s << BUCK_BITS) | (d & (BUCK_SZ - 1));
    }
}

// ---------- pass C: per-bucket degree + row_start + dinv + final CSR scatter ----------
// src_sorted stores BYTE offsets (src*64) for the fp16 row table.
// Block 0 also writes the zero rows (index N) of both fp16 buffers.
__global__ __launch_bounds__(256) void binC_kernel(const int* __restrict__ countsS,
                                                   const int* __restrict__ btot,
                                                   const int* __restrict__ tmp,
                                                   int* __restrict__ src_sorted,
                                                   int* __restrict__ row_start,
                                                   float* __restrict__ dinv,
                                                   __half* __restrict__ bufA,
                                                   __half* __restrict__ bufB,
                                                   int N, int E, int B, int nbuck) {
    __shared__ int hist[BUCK_SZ];
    __shared__ int pre[BUCK_SZ];
    __shared__ int lcur[BUCK_SZ];
    int tid = threadIdx.x;
    int b = blockIdx.x;
    int base = b << BUCK_BITS;
    if (b == 0 && tid < H) {                 // zero rows for padded gathers
        bufA[(size_t)N * H + tid] = __float2half(0.f);
        bufB[(size_t)N * H + tid] = __float2half(0.f);
    }
    int c0 = b * B;
    int e0 = countsS[c0] + btot[c0 >> 8];
    int e1 = E;
    if (b + 1 < nbuck) {
        int c1 = (b + 1) * B;
        e1 = countsS[c1] + btot[c1 >> 8];
    }
    hist[tid] = 0;
    __syncthreads();
    for (int e = e0 + tid; e < e1; e += 256)
        atomicAdd(&hist[tmp[e] & (BUCK_SZ - 1)], 1);
    __syncthreads();
    int v = hist[tid];
    pre[tid] = v;
    __syncthreads();
    for (int off = 1; off < 256; off <<= 1) {
        int t = (tid >= off) ? pre[tid - off] : 0;
        __syncthreads();
        pre[tid] += t;
        __syncthreads();
    }
    int excl = pre[tid] - v;
    int node = base + tid;
    if (node < N) {
        row_start[node] = e0 + excl;
        dinv[node] = rsqrtf((float)v + 1.0f);     // +1 self-loop
        if (node == N - 1) row_start[N] = E;
    }
    lcur[tid] = e0 + excl;
    __syncthreads();
    for (int e = e0 + tid; e < e1; e += 256) {
        int p = tmp[e];
        int pos = atomicAdd(&lcur[p & (BUCK_SZ - 1)], 1);
        src_sorted[pos] = (p >> BUCK_BITS) << 6;   // byte offset of fp16 row
    }
}

// ---------- layer 1 dense: hs1 = fp16( dinv * (x @ W1) ) ----------
// Round-0 version restored verbatim: 8 nodes/block, contiguous W/x staging,
// scalar broadcast LDS reads. 20 VGPR, ~75% occupancy, 0 bank conflicts.
__global__ __launch_bounds__(256) void gemm1_kernel(const float* __restrict__ x,
                                                    const float* __restrict__ W,
                                                    const float* __restrict__ dinv,
                                                    __half* __restrict__ h, int N) {
    __shared__ float Ws[F_IN * H];
    __shared__ float xs[8 * F_IN];
    int tid = threadIdx.x;
    for (int i = tid; i < F_IN * H; i += 256) Ws[i] = W[i];
    int nb = blockIdx.x * 8;
    int navail = N - nb; if (navail > 8) navail = 8;
    const float* xb = x + (long long)nb * F_IN;
    for (int i = tid; i < navail * F_IN; i += 256) xs[i] = xb[i];
    __syncthreads();
    int nl = tid >> 5, f = tid & 31;
    int node = nb + nl;
    if (node < N) {
        float s = 0.f;
        #pragma unroll
        for (int k = 0; k < F_IN; k++) s += xs[nl * F_IN + k] * Ws[k * H + f];
        h[(long long)node * H + f] = __float2half(s * dinv[node]);
    }
}

// ---------- fused agg + GEMM (dwordx2 gathers, SINGLE latency round/chunk) ----
// Lane map per node (32 lanes): slot = lane>>3 (edge slot 0..3), fq = lane&7
// (feature quad: 8 fq lanes cover one 64B row contiguously -> coalesced).
// ALL 8 uint2 gathers of a 32-edge chunk are issued before any consumption:
// one L2/L3 latency visit per chunk instead of two (j=0/j=16 rounds).
// Out-of-range slots gather the hot ZERO ROW (byte offset N*64, L1-resident).
// Accumulation order is identical to the 2-round version (bitwise-same result).
__global__ __launch_bounds__(256) void agg_gemm_kernel(const int* __restrict__ row_start,
                                                       const int* __restrict__ src_sorted,
                                                       const float* __restrict__ dinv,
                                                       const __half* __restrict__ hs,
                                                       const float* __restrict__ b,
                                                       const float* __restrict__ Wn,
                                                       __half* __restrict__ hout, int N) {
    __shared__ float Wp[16 * 64];          // Wp[k2*64 + 2f + (k&1)] = Wn[k*32+f]
    __shared__ float t[8 * H];
    int tid = threadIdx.x;
    for (int i = tid; i < 1024; i += 256) {
        int k2 = i >> 6, rem = i & 63;
        int f = rem >> 1, kk = (k2 << 1) | (rem & 1);
        Wp[i] = Wn[kk * H + f];
    }
    int nl = tid >> 5;
    int lane32 = tid & 31;
    int slot = lane32 >> 3;
    int fq = lane32 & 7;
    int node = blockIdx.x * 8 + nl;
    int zoff = N << 6;
    __half2 z = __floats2half2_rn(0.f, 0.f);
    __half2 a0 = z, a1 = z, a2 = z, a3 = z;
    if (node < N) {
        const char* hbase = (const char*)hs + (fq << 3);
        int e0 = row_start[node], e1 = row_start[node + 1];
        int idxv = (e0 + lane32 < e1) ? src_sorted[e0 + lane32] : zoff;
        for (int base = e0; base < e1; base += 32) {
            int idxN = (base + 32 + lane32 < e1) ? src_sorted[base + 32 + lane32] : zoff;
            int offs[8];
            #pragma unroll
            for (int k = 0; k < 8; k++)
                offs[k] = __shfl(idxv, ((k >> 2) << 4) + ((k & 3) << 2) + slot, 32);
            uint2 g[8];
            #pragma unroll
            for (int k = 0; k < 8; k++) g[k] = *(const uint2*)(hbase + offs[k]);
            a0 = __hadd2(a0, *(__half2*)&g[0].x);
            a1 = __hadd2(a1, *(__half2*)&g[0].y);
            a2 = __hadd2(a2, *(__half2*)&g[1].x);
            a3 = __hadd2(a3, *(__half2*)&g[1].y);
            a0 = __hadd2(a0, *(__half2*)&g[2].x);
            a1 = __hadd2(a1, *(__half2*)&g[2].y);
            a2 = __hadd2(a2, *(__half2*)&g[3].x);
            a3 = __hadd2(a3, *(__half2*)&g[3].y);
            a0 = __hadd2(a0, *(__half2*)&g[4].x);
            a1 = __hadd2(a1, *(__half2*)&g[4].y);
            a2 = __hadd2(a2, *(__half2*)&g[5].x);
            a3 = __hadd2(a3, *(__half2*)&g[5].y);
            a0 = __hadd2(a0, *(__half2*)&g[6].x);
            a1 = __hadd2(a1, *(__half2*)&g[6].y);
            a2 = __hadd2(a2, *(__half2*)&g[7].x);
            a3 = __hadd2(a3, *(__half2*)&g[7].y);
            idxv = idxN;
        }
    }
    a0 = __hadd2(a0, a2);
    a1 = __hadd2(a1, a3);
    a0 = __hadd2(a0, h2_shfl_xor(a0, 8));
    a1 = __hadd2(a1, h2_shfl_xor(a1, 8));
    a0 = __hadd2(a0, h2_shfl_xor(a0, 16));
    a1 = __hadd2(a1, h2_shfl_xor(a1, 16));
    if (node < N && lane32 < 8) {
        float di = dinv[node];
        uint2 sv = *(const uint2*)((const char*)hs + ((long long)node << 6) + (fq << 3));
        float2 f0 = __half22float2(a0), f1 = __half22float2(a1);
        float2 s0 = __half22float2(*(__half2*)&sv.x);
        float2 s1 = __half22float2(*(__half2*)&sv.y);
        float4 bv = ((const float4*)b)[fq];
        float4 r;
        r.x = fmaxf(di * (f0.x + s0.x) + bv.x, 0.f);
        r.y = fmaxf(di * (f0.y + s0.y) + bv.y, 0.f);
        r.z = fmaxf(di * (f1.x + s1.x) + bv.z, 0.f);
        r.w = fmaxf(di * (f1.y + s1.y) + bv.w, 0.f);
        ((float4*)&t[nl * H])[fq] = r;
    }
    __syncthreads();
    if (node < N) {
        int f = lane32;
        float s = 0.f;
        #pragma unroll
        for (int k2 = 0; k2 < 16; k2++) {
            float2 xv = *(const float2*)&t[nl * H + (k2 << 1)];
            float2 wv = *(const float2*)&Wp[(k2 << 6) + (f << 1)];
            s += xv.x * wv.x + xv.y * wv.y;
        }
        hout[(long long)node * H + f] = __float2half(s * dinv[node]);
    }
}

// ---------- final layer: X5 = relu(...), pool into 64 spread copies ----------
__global__ __launch_bounds__(256) void agg_pool_kernel(const int* __restrict__ row_start,
                                                       const int* __restrict__ src_sorted,
                                                       const float* __restrict__ dinv,
                                                       const __half* __restrict__ hs,
                                                       const float* __restrict__ b,
                                                       float* __restrict__ gs, int N) {
    __shared__ float t[8 * H];
    int tid = threadIdx.x;
    int nl = tid >> 5;
    int lane32 = tid & 31;
    int slot = lane32 >> 3;
    int fq = lane32 & 7;
    int node = blockIdx.x * 8 + nl;
    int zoff = N << 6;
    __half2 z = __floats2half2_rn(0.f, 0.f);
    __half2 a0 = z, a1 = z, a2 = z, a3 = z;
    if (node < N) {
        const char* hbase = (const char*)hs + (fq << 3);
        int e0 = row_start[node], e1 = row_start[node + 1];
        int idxv = (e0 + lane32 < e1) ? src_sorted[e0 + lane32] : zoff;
        for (int base = e0; base < e1; base += 32) {
            int idxN = (base + 32 + lane32 < e1) ? src_sorted[base + 32 + lane32] : zoff;
            int offs[8];
            #pragma unroll
            for (int k = 0; k < 8; k++)
                offs[k] = __shfl(idxv, ((k >> 2) << 4) + ((k & 3) << 2) + slot, 32);
            uint2 g[8];
            #pragma unroll
            for (int k = 0; k < 8; k++) g[k] = *(const uint2*)(hbase + offs[k]);
            a0 = __hadd2(a0, *(__half2*)&g[0].x);
            a1 = __hadd2(a1, *(__half2*)&g[0].y);
            a2 = __hadd2(a2, *(__half2*)&g[1].x);
            a3 = __hadd2(a3, *(__half2*)&g[1].y);
            a0 = __hadd2(a0, *(__half2*)&g[2].x);
            a1 = __hadd2(a1, *(__half2*)&g[2].y);
            a2 = __hadd2(a2, *(__half2*)&g[3].x);
            a3 = __hadd2(a3, *(__half2*)&g[3].y);
            a0 = __hadd2(a0, *(__half2*)&g[4].x);
            a1 = __hadd2(a1, *(__half2*)&g[4].y);
            a2 = __hadd2(a2, *(__half2*)&g[5].x);
            a3 = __hadd2(a3, *(__half2*)&g[5].y);
            a0 = __hadd2(a0, *(__half2*)&g[6].x);
            a1 = __hadd2(a1, *(__half2*)&g[6].y);
            a2 = __hadd2(a2, *(__half2*)&g[7].x);
            a3 = __hadd2(a3, *(__half2*)&g[7].y);
            idxv = idxN;
        }
    }
    a0 = __hadd2(a0, a2);
    a1 = __hadd2(a1, a3);
    a0 = __hadd2(a0, h2_shfl_xor(a0, 8));
    a1 = __hadd2(a1, h2_shfl_xor(a1, 8));
    a0 = __hadd2(a0, h2_shfl_xor(a0, 16));
    a1 = __hadd2(a1, h2_shfl_xor(a1, 16));
    if (lane32 < 8) {
        float4 r = make_float4(0.f, 0.f, 0.f, 0.f);
        if (node < N) {
            float di = dinv[node];
            uint2 sv = *(const uint2*)((const char*)hs + ((long long)node << 6) + (fq << 3));
            float2 f0 = __half22float2(a0), f1 = __half22float2(a1);
            float2 s0 = __half22float2(*(__half2*)&sv.x);
            float2 s1 = __half22float2(*(__half2*)&sv.y);
            float4 bv = ((const float4*)b)[fq];
            r.x = fmaxf(di * (f0.x + s0.x) + bv.x, 0.f);
            r.y = fmaxf(di * (f0.y + s0.y) + bv.y, 0.f);
            r.z = fmaxf(di * (f1.x + s1.x) + bv.z, 0.f);
            r.w = fmaxf(di * (f1.y + s1.y) + bv.w, 0.f);
        }
        ((float4*)&t[nl * H])[fq] = r;
    }
    __syncthreads();
    if (tid < H) {
        float s = 0.f;
        #pragma unroll
        for (int rI = 0; rI < 8; rI++) s += t[rI * H + tid];
        atomicAdd(&gs[(blockIdx.x & 63) * H + tid], s);
    }
}

// ---------- head ----------
__global__ __launch_bounds__(64) void head_kernel(const float* __restrict__ gs,
                                                  const float* __restrict__ Wl1,
                                                  const float* __restrict__ bl1,
                                                  const float* __restrict__ Wl2,
                                                  const float* __restrict__ bl2,
                                                  float* __restrict__ out) {
    __shared__ float gg[H];
    __shared__ float t[16];
    int tid = threadIdx.x;
    if (tid < H) {
        float s = 0.f;
        for (int c = 0; c < 64; c++) s += gs[c * H + tid];
        gg[tid] = s;
    }
    __syncthreads();
    if (tid < 16) {
        float s = bl1[tid];
        #pragma unroll
        for (int k = 0; k < 32; k++) s += gg[k] * Wl1[k * 16 + tid];
        t[tid] = fmaxf(s, 0.f);
    }
    __syncthreads();
    if (tid < 3) {
        float s = bl2[tid];
        #pragma unroll
        for (int k = 0; k < 16; k++) s += t[k] * Wl2[k * 3 + tid];
        out[tid] = s;
    }
}

extern "C" void kernel_launch(void* const* d_in, const int* in_sizes, int n_in,
                              void* d_out, int out_size, void* d_ws, size_t ws_size,
                              hipStream_t stream) {
    const float* x   = (const float*)d_in[0];
    const int*   ei  = (const int*)d_in[1];
    const float* W1  = (const float*)d_in[2];
    const float* b1  = (const float*)d_in[3];
    const float* W2  = (const float*)d_in[4];
    const float* b2  = (const float*)d_in[5];
    const float* W3  = (const float*)d_in[6];
    const float* b3  = (const float*)d_in[7];
    const float* W4  = (const float*)d_in[8];
    const float* b4  = (const float*)d_in[9];
    const float* Wl1 = (const float*)d_in[10];
    const float* bl1 = (const float*)d_in[11];
    const float* Wl2 = (const float*)d_in[12];
    const float* bl2 = (const float*)d_in[13];
    float* out = (float*)d_out;

    const int N = in_sizes[0] / F_IN;
    const int E = in_sizes[1] / 2;
    const int nbuck = (N + BUCK_SZ - 1) >> BUCK_BITS;      // 586 for N=150000
    const int B = (E + CHUNK - 1) / CHUNK;                 // 293 for E=2.4M
    const int nC = nbuck * B;

    char* ws = (char*)d_ws;
    size_t off = 0;
    auto alloc = [&](size_t bytes) {
        char* p = ws + off;
        off += (bytes + 255) & ~(size_t)255;
        return p;
    };
    float* dinv       = (float*)alloc((size_t)N * 4);
    int*   row_start  = (int*)alloc((size_t)(N + 1) * 4);
    int*   counts     = (int*)alloc((size_t)nC * 4);
    int*   countsS    = (int*)alloc((size_t)nC * 4);
    int*   btot2      = (int*)alloc(((size_t)nC / 256 + 2) * 4);
    int*   src_sorted = (int*)alloc((size_t)E * 4);
    int*   tmp        = (int*)alloc((size_t)E * 4);
    __half* bufA      = (__half*)alloc((size_t)(N + 1) * H * 2);   // fp16 rows + zero row
    __half* bufB      = (__half*)alloc((size_t)(N + 1) * H * 2);
    float* gs         = (float*)alloc(64 * H * 4);

    const int TB = 256;
    const int gC  = (nC + TB - 1) / TB;   // 675 blocks <= 1024 for scan2
    const int gN8 = (N + 7) / 8;

    // ---- CSR build (no global atomics, no memsets — all folded) ----
    histA_kernel<<<B, TB, 0, stream>>>(ei, counts, gs, E, B, nbuck);
    scan1_kernel<<<gC, TB, 0, stream>>>(counts, countsS, btot2, nC);
    scan2_kernel<<<1, 1024, 0, stream>>>(btot2, gC);
    binB_kernel<<<B, TB, 0, stream>>>(ei, countsS, btot2, tmp, E, B, nbuck);
    binC_kernel<<<nbuck, TB, 0, stream>>>(countsS, btot2, tmp, src_sorted, row_start,
                                          dinv, bufA, bufB, N, E, B, nbuck);

    // ---- layers ----
    gemm1_kernel<<<gN8, TB, 0, stream>>>(x, W1, dinv, bufA, N);                                  // hs1
    agg_gemm_kernel<<<gN8, TB, 0, stream>>>(row_start, src_sorted, dinv, bufA, b1, W2, bufB, N); // hs2
    agg_gemm_kernel<<<gN8, TB, 0, stream>>>(row_start, src_sorted, dinv, bufB, b2, W3, bufA, N); // hs3
    agg_gemm_kernel<<<gN8, TB, 0, stream>>>(row_start, src_sorted, dinv, bufA, b3, W4, bufB, N); // hs4
    agg_pool_kernel<<<gN8, TB, 0, stream>>>(row_start, src_sorted, dinv, bufB, b4, gs, N);       // pool(X5)

    head_kernel<<<1, 64, 0, stream>>>(gs, Wl1, bl1, Wl2, bl2, out);
}